// Round 4
// baseline (1456.655 us; speedup 1.0000x reference)
//
#include <hip/hip_runtime.h>

typedef _Float16 f16;
typedef _Float16 f16x8 __attribute__((ext_vector_type(8)));
typedef f16x8 f16x8a __attribute__((may_alias));
typedef float f32x4 __attribute__((ext_vector_type(4)));

#define NTOK 21120          // 4 * 5280 tokens
#define MPAD 21248          // NTOK padded to 256-row tiles
#define SCALE_Q 0.18033688f // (1/8) * log2(e)

__device__ __forceinline__ void gll16(const void* g, void* l) {
  __builtin_amdgcn_global_load_lds(
      (const __attribute__((address_space(1))) unsigned int*)g,
      (__attribute__((address_space(3))) unsigned int*)l, 16, 0, 0);
}

__device__ __forceinline__ unsigned int pack2(float a, float b) {
  union { f16 h[2]; unsigned int u; } c;
  c.h[0] = (f16)a; c.h[1] = (f16)b;
  return c.u;
}
__device__ __forceinline__ unsigned short f2h(float a) {
  union { f16 h; unsigned short u; } c; c.h = (f16)a; return c.u;
}

// DPP cross-lane (VALU pipe, no DS ops). 0xB1=quad xor1, 0x4E=quad xor2,
// 0x141=row_half_mirror, 0x140=row_mirror
template <int C>
__device__ __forceinline__ float dppf(float x) {
  union { float f; int i; } u, r;
  u.f = x;
  r.i = __builtin_amdgcn_update_dpp(0, u.i, C, 0xf, 0xf, true);
  return r.f;
}

// ---------------------------------------------------------------- casts
__global__ __launch_bounds__(256) void cast_kernel(
    const float* __restrict__ in, unsigned short* __restrict__ out, int n4) {
  int i = blockIdx.x * 256 + threadIdx.x;
  if (i >= n4) return;
  float4 v = ((const float4*)in)[i];
  uint2 o;
  o.x = pack2(v.x, v.y);
  o.y = pack2(v.z, v.w);
  ((uint2*)out)[i] = o;
}

// transpose + cast 1024x1024 f32 -> f16 (out[d][c] = in[c][d])
__global__ __launch_bounds__(256) void transpose_cast_kernel(
    const float* __restrict__ in, unsigned short* __restrict__ out) {
  __shared__ float tile[32][33];
  int bx = blockIdx.x & 31, by = blockIdx.x >> 5;
  int tx = threadIdx.x & 31, ty = threadIdx.x >> 5;
#pragma unroll
  for (int i = 0; i < 32; i += 8)
    tile[ty + i][tx] = in[(size_t)(by * 32 + ty + i) * 1024 + bx * 32 + tx];
  __syncthreads();
#pragma unroll
  for (int i = 0; i < 32; i += 8)
    out[(size_t)(bx * 32 + ty + i) * 1024 + by * 32 + tx] = f2h(tile[tx][ty + i]);
}

// bc[e] = sum_c wtqkv[e][c] * bsproj[c]   (e in [0,3072))
__global__ __launch_bounds__(256) void bias_combine_kernel(
    const float* __restrict__ w, const float* __restrict__ b, float* __restrict__ bc) {
  int e = blockIdx.x * 256 + threadIdx.x;
  if (e >= 3072) return;
  const float4* wr = (const float4*)(w + (size_t)e * 1024);
  const float4* b4 = (const float4*)b;
  float s = 0.f;
  for (int c = 0; c < 256; ++c) {
    float4 wv = wr[c], bv = b4[c];
    s += wv.x * bv.x + wv.y * bv.y + wv.z * bv.z + wv.w * bv.w;
  }
  bc[e] = s;
}

// ---------------------------------------------------------------- rope tables
__global__ __launch_bounds__(256) void rope_table_kernel(float2* tabS, float2* tabT) {
  int t = blockIdx.x * 256 + threadIdx.x;
  const float lb = logf(10000.0f) * (1.0f / 32.0f);
  if (t < 220 * 32) {
    int s = t >> 5, i = t & 31;
    float theta = expf(-(float)i * lb);
    float ang = (float)s * theta;
    tabS[t] = make_float2(cosf(ang), sinf(ang));
  } else if (t < 220 * 32 + 24 * 32) {
    int u = t - 220 * 32;
    int s = u >> 5, i = u & 31;
    float theta = expf(-(float)i * lb);
    float ang = (float)s * theta;
    tabT[u] = make_float2(cosf(ang), sinf(ang));
  }
}

// ---------------------------------------------------------------- small GEMM (kept for Wc)
__global__ __launch_bounds__(256) void gemm_bt(
    const unsigned short* __restrict__ A, const unsigned short* __restrict__ B,
    const float* __restrict__ bias, void* __restrict__ C,
    int M, int N, int K, int outmode,
    const float2* __restrict__ tab, const float* __restrict__ gq,
    const float* __restrict__ gk, int mode) {
  __shared__ __align__(16) unsigned short sh[16384];
  unsigned short* As = sh;
  unsigned short* Bs = sh + 8192;
  const int tid = threadIdx.x;
  const int w = tid >> 6, lane = tid & 63;
  const int l15 = lane & 15, quad = lane >> 4;
  const int wr = w >> 1, wc = w & 1;

  const int ntn = N >> 7;
  const int stride = ntn << 3;
  const int g = blockIdx.x / stride, r = blockIdx.x % stride;
  const int tn = r % ntn, tm = g * 8 + r / ntn;

  f32x4 acc[4][4];
#pragma unroll
  for (int a = 0; a < 4; ++a)
#pragma unroll
    for (int b = 0; b < 4; ++b) acc[a][b] = (f32x4){0.f, 0.f, 0.f, 0.f};

  const int srow = tid >> 3;
  const int schk = tid & 7;
  const size_t arow0 = (size_t)tm * 128;
  const size_t brow0 = (size_t)tn * 128;
  const int nk = K >> 6;

  for (int kt = 0; kt < nk; ++kt) {
    __syncthreads();
    const int kb = kt << 6;
#pragma unroll
    for (int rd = 0; rd < 4; ++rd) {
      int row = rd * 32 + srow;
      int sc = (schk ^ (row & 7)) * 8;
      gll16(A + (arow0 + row) * K + kb + sc, (char*)As + rd * 4096 + tid * 16);
      gll16(B + (brow0 + row) * K + kb + sc, (char*)Bs + rd * 4096 + tid * 16);
    }
    __syncthreads();
#pragma unroll
    for (int kk = 0; kk < 2; ++kk) {
      f16x8 af[4], bf[4];
#pragma unroll
      for (int mt = 0; mt < 4; ++mt) {
        int ra = wr * 64 + mt * 16 + l15;
        af[mt] = *(const f16x8a*)((const char*)As + ra * 128 + (((kk * 4 + quad) ^ (ra & 7)) * 16));
        int rb = wc * 64 + mt * 16 + l15;
        bf[mt] = *(const f16x8a*)((const char*)Bs + rb * 128 + (((kk * 4 + quad) ^ (rb & 7)) * 16));
      }
#pragma unroll
      for (int mt = 0; mt < 4; ++mt)
#pragma unroll
        for (int nt = 0; nt < 4; ++nt)
          acc[mt][nt] = __builtin_amdgcn_mfma_f32_16x16x32_f16(af[mt], bf[nt], acc[mt][nt], 0, 0, 0);
    }
  }

  // f16 epilogue: 2 passes through LDS (64 x 128, stride 136)
  unsigned short* Cs = (unsigned short*)C;
#pragma unroll
  for (int p = 0; p < 2; ++p) {
    __syncthreads();
#pragma unroll
    for (int mi = 0; mi < 2; ++mi) {
      int mt = p * 2 + mi;
      int rl = wr * 32 + mi * 16 + quad * 4;
#pragma unroll
      for (int nt = 0; nt < 4; ++nt) {
        int cl = wc * 64 + nt * 16 + l15;
#pragma unroll
        for (int rg = 0; rg < 4; ++rg)
          sh[(rl + rg) * 136 + cl] = f2h(acc[mt][nt][rg]);
      }
    }
    __syncthreads();
#pragma unroll
    for (int c = 0; c < 4; ++c) {
      int rl = c * 16 + (tid >> 4), cx = tid & 15;
      int grow = tm * 128 + ((rl >> 5) << 6) + p * 32 + (rl & 31);
      uint4 v = *(const uint4*)&sh[rl * 136 + cx * 8];
      *(uint4*)&Cs[(size_t)grow * N + tn * 128 + cx * 8] = v;
    }
  }
}

// ---------------------------------------------------------------- big GEMM: 256x256 tile, persistent
// 8 waves, per-wave 128x64 C. K=1024 hard (16 tiles of BK=64).
// LDS 160 KB: A ring = 3 tiles (32 KB each), B ring = 2 tiles.
// Main loop (per sweep): ONE barrier per K-tile, counted lgkm quadrant sequencing,
// vmcnt(4) per tile; stage B(t+1) early, A(t+2) late.
// PERSISTENT: cpb output tiles per block (same tm, consecutive tn). Between sweeps,
// next tile's A(0),B(0),A(1) are staged into the (dead) ring immediately after the
// final K-tile barrier, BEFORE the epilogue — the epilogue hides the L3/L2 fetch.
// Epilogue scratch lives in ASLOT(2) (4 KB/wave, chunked flushes) so it cannot
// collide with the pre-staged slots. QKV: grid 249 = 83 tm x 3 j, cpb=4 (996 tiles,
// exactly 4/block, zero tail). Proj: grid 332, cpb=1.
#define FENCE() asm volatile("" ::: "memory")
#define BAR() do { FENCE(); __builtin_amdgcn_s_barrier(); FENCE(); } while (0)
#define WAITV(N) asm volatile("s_waitcnt vmcnt(" #N ")" ::: "memory")
#define WAITL(N) do { asm volatile("s_waitcnt lgkmcnt(" #N ")" ::: "memory"); \
                      __builtin_amdgcn_sched_barrier(0); } while (0)
#define ASLOT(T) (((T) % 3) * 32768)
#define BSLOT(T) (98304 + ((T) & 1) * 32768)
#define LDAf(T, mt, kk) (*(const f16x8a*)(smem + ASLOT(T) + wrOff + (mt) * 2048 + (aoff ^ ((kk) << 6))))
#define LDBf(T, nt, kk) (*(const f16x8a*)(smem + BSLOT(T) + bcOff + (nt) * 2048 + (aoff ^ ((kk) << 6))))
#define STAGE_A2(T, h) do { \
    gll16(aSp + (size_t)((h) * 128) * K + (T) * 64, smem + ASLOT(T) + (h) * 16384 + tid * 16); \
    gll16(aSp + (size_t)((h) * 128 + 64) * K + (T) * 64, smem + ASLOT(T) + (h) * 16384 + 8192 + tid * 16); \
  } while (0)
#define STAGE_B2(P, T, h) do { \
    gll16((P) + (size_t)((h) * 128) * K + (T) * 64, smem + BSLOT(T) + (h) * 16384 + tid * 16); \
    gll16((P) + (size_t)((h) * 128 + 64) * K + (T) * 64, smem + BSLOT(T) + (h) * 16384 + 8192 + tid * 16); \
  } while (0)
#define MM16(QB, A0_, A1_, A2_, A3_, B0_, B1_, B2_, B3_) do { \
    acc[QB + 0][0] = __builtin_amdgcn_mfma_f32_16x16x32_f16(A0_, B0_, acc[QB + 0][0], 0, 0, 0); \
    acc[QB + 0][1] = __builtin_amdgcn_mfma_f32_16x16x32_f16(A0_, B1_, acc[QB + 0][1], 0, 0, 0); \
    acc[QB + 0][2] = __builtin_amdgcn_mfma_f32_16x16x32_f16(A0_, B2_, acc[QB + 0][2], 0, 0, 0); \
    acc[QB + 0][3] = __builtin_amdgcn_mfma_f32_16x16x32_f16(A0_, B3_, acc[QB + 0][3], 0, 0, 0); \
    acc[QB + 1][0] = __builtin_amdgcn_mfma_f32_16x16x32_f16(A1_, B0_, acc[QB + 1][0], 0, 0, 0); \
    acc[QB + 1][1] = __builtin_amdgcn_mfma_f32_16x16x32_f16(A1_, B1_, acc[QB + 1][1], 0, 0, 0); \
    acc[QB + 1][2] = __builtin_amdgcn_mfma_f32_16x16x32_f16(A1_, B2_, acc[QB + 1][2], 0, 0, 0); \
    acc[QB + 1][3] = __builtin_amdgcn_mfma_f32_16x16x32_f16(A1_, B3_, acc[QB + 1][3], 0, 0, 0); \
    acc[QB + 2][0] = __builtin_amdgcn_mfma_f32_16x16x32_f16(A2_, B0_, acc[QB + 2][0], 0, 0, 0); \
    acc[QB + 2][1] = __builtin_amdgcn_mfma_f32_16x16x32_f16(A2_, B1_, acc[QB + 2][1], 0, 0, 0); \
    acc[QB + 2][2] = __builtin_amdgcn_mfma_f32_16x16x32_f16(A2_, B2_, acc[QB + 2][2], 0, 0, 0); \
    acc[QB + 2][3] = __builtin_amdgcn_mfma_f32_16x16x32_f16(A2_, B3_, acc[QB + 2][3], 0, 0, 0); \
    acc[QB + 3][0] = __builtin_amdgcn_mfma_f32_16x16x32_f16(A3_, B0_, acc[QB + 3][0], 0, 0, 0); \
    acc[QB + 3][1] = __builtin_amdgcn_mfma_f32_16x16x32_f16(A3_, B1_, acc[QB + 3][1], 0, 0, 0); \
    acc[QB + 3][2] = __builtin_amdgcn_mfma_f32_16x16x32_f16(A3_, B2_, acc[QB + 3][2], 0, 0, 0); \
    acc[QB + 3][3] = __builtin_amdgcn_mfma_f32_16x16x32_f16(A3_, B3_, acc[QB + 3][3], 0, 0, 0); \
  } while (0)

__global__ __launch_bounds__(512, 2) void gemm256(
    const unsigned short* __restrict__ A, const unsigned short* __restrict__ B,
    const float* __restrict__ bias, void* __restrict__ C,
    int M, int N, int K, int outmode,
    const float2* __restrict__ tab, const float* __restrict__ gq,
    const float* __restrict__ gk, int mode, int cpb) {
  extern __shared__ char smem[];
  const int tid = threadIdx.x;
  const int w = tid >> 6, lane = tid & 63;
  const int l15 = lane & 15, quad = lane >> 4;
  const int wr = w >> 2, wc = w & 3;

  // XCD-bijective swizzle (nwg % 8 != 0 safe)
  const int nwg = gridDim.x;
  const int qd = nwg >> 3, rm = nwg & 7;
  const int xcd = blockIdx.x & 7, lin = blockIdx.x >> 3;
  const int wgid = (xcd < rm ? xcd * (qd + 1) : rm * (qd + 1) + (xcd - rm) * qd) + lin;
  int tm, tn0;
  if (cpb > 1) {
    tm = wgid % 83;            // same-XCD blocks share j (B-panel L2 locality)
    tn0 = (wgid / 83) * cpb;
  } else {
    const int ntn = N >> 8;
    const int stg = ntn << 3;
    const int g = wgid / stg, r2 = wgid % stg;
    tn0 = r2 % ntn; tm = g * 8 + r2 / ntn;
  }

  const int wrOff = wr * 16384;
  const int bcOff = (wc >> 1) * 16384 + (wc & 1) * 8192;
  const int aoff = l15 * 128 + ((quad ^ (l15 & 7)) << 4);

  // staging source (pre-swizzled column so LDS dest stays lane-linear)
  const int sc = ((tid & 7) ^ ((tid >> 3) & 7)) * 8;
  const unsigned short* aSp = A + (size_t)(tm * 256 + (tid >> 3)) * K + sc;
  const unsigned short* bSp = B + (size_t)(tn0 * 256 + (tid >> 3)) * K + sc;

  const size_t grow0 = (size_t)tm * 256 + wr * 128;
  unsigned short* C16 = (unsigned short*)C;

  // initial prologue: A[0], B[0], A[1]; vmcnt(4) -> A0,B0 confirmed, A1 in flight
  STAGE_A2(0, 0); STAGE_A2(0, 1);
  STAGE_B2(bSp, 0, 0); STAGE_B2(bSp, 0, 1);
  STAGE_A2(1, 0); STAGE_A2(1, 1);
  WAITV(4);
  BAR();

  for (int c = 0; c < cpb; ++c) {
    const int tn = tn0 + c;
    f32x4 acc[8][4];
#pragma unroll
    for (int i = 0; i < 8; ++i)
#pragma unroll
      for (int j = 0; j < 4; ++j) acc[i][j] = (f32x4){0.f, 0.f, 0.f, 0.f};

#pragma unroll
    for (int t = 0; t < 16; ++t) {
      f16x8 bA0, bA1, bA2, bA3, bB0, bB1, bB2, bB3;
      f16x8 aA0, aA1, aA2, aA3, aB0, aB1, aB2, aB3;
      f16x8 aC0, aC1, aC2, aC3, aD0, aD1, aD2, aD3;
      // R0 (8 ds): B k0 + A rows0-3 k0
      bA0 = LDBf(t, 0, 0); bA1 = LDBf(t, 1, 0); bA2 = LDBf(t, 2, 0); bA3 = LDBf(t, 3, 0);
      aA0 = LDAf(t, 0, 0); aA1 = LDAf(t, 1, 0); aA2 = LDAf(t, 2, 0); aA3 = LDAf(t, 3, 0);
      // R1 (4 ds): A rows4-7 k0
      aB0 = LDAf(t, 4, 0); aB1 = LDAf(t, 5, 0); aB2 = LDAf(t, 6, 0); aB3 = LDAf(t, 7, 0);
      if (t <= 14) { STAGE_B2(bSp, t + 1, 0); STAGE_B2(bSp, t + 1, 1); }
      WAITL(4);                                   // R0 done, R1 may fly
      __builtin_amdgcn_s_setprio(1);
      MM16(0, aA0, aA1, aA2, aA3, bA0, bA1, bA2, bA3);
      __builtin_amdgcn_s_setprio(0);
      // R2 (8 ds): B k1 + A rows0-3 k1 (overlaps Q0/Q1 MFMAs)
      bB0 = LDBf(t, 0, 1); bB1 = LDBf(t, 1, 1); bB2 = LDBf(t, 2, 1); bB3 = LDBf(t, 3, 1);
      aC0 = LDAf(t, 0, 1); aC1 = LDAf(t, 1, 1); aC2 = LDAf(t, 2, 1); aC3 = LDAf(t, 3, 1);
      WAITL(8);                                   // R1 done, R2 may fly
      __builtin_amdgcn_s_setprio(1);
      MM16(4, aB0, aB1, aB2, aB3, bA0, bA1, bA2, bA3);
      __builtin_amdgcn_s_setprio(0);
      // R3 (4 ds): A rows4-7 k1
      aD0 = LDAf(t, 4, 1); aD1 = LDAf(t, 5, 1); aD2 = LDAf(t, 6, 1); aD3 = LDAf(t, 7, 1);
      if (t <= 13) { STAGE_A2(t + 2, 0); STAGE_A2(t + 2, 1); }
      WAITL(4);                                   // R2 done, R3 may fly
      __builtin_amdgcn_s_setprio(1);
      MM16(0, aC0, aC1, aC2, aC3, bB0, bB1, bB2, bB3);
      __builtin_amdgcn_s_setprio(0);
      WAITL(0);                                   // R3 done
      __builtin_amdgcn_s_setprio(1);
      MM16(4, aD0, aD1, aD2, aD3, bB0, bB1, bB2, bB3);
      __builtin_amdgcn_s_setprio(0);
      if (t <= 13) { WAITV(4); } else if (t == 14) { WAITV(0); }
      BAR();                                      // the only barrier per K-tile
    }

    // ---- cross-tile pre-stage: ring is fully dead here; epilogue hides the fetch
    const unsigned short* bSpN = bSp + (size_t)256 * K;
    if (c + 1 < cpb) {
      STAGE_A2(0, 0); STAGE_A2(0, 1);
      STAGE_B2(bSpN, 0, 0); STAGE_B2(bSpN, 0, 1);
      STAGE_A2(1, 0); STAGE_A2(1, 1);
    }

    // ---------------- epilogue: per-wave private 4KB scratch in ASLOT(2)
    const int gcol0 = tn * 256 + wc * 64;
    float bl[4] = {0.f, 0.f, 0.f, 0.f};
    if (bias != nullptr) {
#pragma unroll
      for (int nt = 0; nt < 4; ++nt) bl[nt] = bias[gcol0 + nt * 16 + l15];
    }

    if (outmode == 2) {
      // f32 + bias: 8 chunks of 16 rows (4KB each)
      float* wf = (float*)(smem + 65536 + w * 4096);
      const int frw = lane >> 4, fc = lane & 15;
#pragma unroll
      for (int mt = 0; mt < 8; ++mt) {
#pragma unroll
        for (int nt = 0; nt < 4; ++nt)
#pragma unroll
          for (int rg = 0; rg < 4; ++rg) {
            int rl = quad * 4 + rg;
            int col = nt * 16 + l15;
            int cq = col >> 2, lo = col & 3;
            wf[rl * 64 + ((cq ^ rl) << 2) + lo] = acc[mt][nt][rg] + bl[nt];
          }
#pragma unroll
        for (int it = 0; it < 4; ++it) {
          int rl = it * 4 + frw;
          float4 v = *(const float4*)(wf + rl * 64 + ((fc ^ rl) << 2));
          size_t gr = grow0 + mt * 16 + rl;
          if (gr < (size_t)M)
            *(float4*)((float*)C + gr * N + gcol0 + fc * 4) = v;
        }
      }
    } else {
      unsigned short* wh = (unsigned short*)(smem + 65536 + w * 4096);
      const int frow = lane >> 3, fch = lane & 7;
      if (outmode == 3 && tn < 8) {
        // fused RMSNorm + gain + RoPE: one head per wave; 4 chunks of 32 rows
        const int isQ = tn < 4;
        const float* gg = isQ ? gq : gk;
        float gv[4];
#pragma unroll
        for (int nt = 0; nt < 4; ++nt) gv[nt] = gg[nt * 16 + l15];
#pragma unroll
        for (int mp = 0; mp < 4; ++mp) {
#pragma unroll
          for (int mi = 0; mi < 2; ++mi) {
            const int mt = mp * 2 + mi;
            float v[4][4], rr[4];
#pragma unroll
            for (int rg = 0; rg < 4; ++rg) rr[rg] = 0.f;
#pragma unroll
            for (int nt = 0; nt < 4; ++nt)
#pragma unroll
              for (int rg = 0; rg < 4; ++rg) {
                float x = acc[mt][nt][rg] + bl[nt];
                v[nt][rg] = x;
                rr[rg] += x * x;
              }
#pragma unroll
            for (int rg = 0; rg < 4; ++rg) {
              float s = rr[rg];
              s += dppf<0xB1>(s);   // 16-lane butterfly sum, VALU-only
              s += dppf<0x4E>(s);
              s += dppf<0x141>(s);
              s += dppf<0x140>(s);
              float r = rsqrtf(s * (1.0f / 64.0f) + 1e-6f);
              rr[rg] = isQ ? r * SCALE_Q : r;
            }
            int pos[4];
#pragma unroll
            for (int rg = 0; rg < 4; ++rg) {
              int grow = (int)grow0 + mt * 16 + quad * 4 + rg;
              pos[rg] = mode ? ((grow / 220) % 24) : (grow % 220);
            }
#pragma unroll
            for (int nt = 0; nt < 4; ++nt) {
              int col = nt * 16 + l15;
              int ii = nt * 8 + (l15 >> 1);
              int cc = col >> 3, lo = col & 7;
#pragma unroll
              for (int rg = 0; rg < 4; ++rg) {
                float2 cs = tab[pos[rg] * 32 + ii];
                float x = v[nt][rg] * rr[rg] * gv[nt];
                float p = dppf<0xB1>(x);  // pair partner (adjacent lane)
                float o = (l15 & 1) ? (x * cs.x + p * cs.y) : (x * cs.x - p * cs.y);
                int rl = mi * 16 + quad * 4 + rg;   // row within 32-row chunk
                wh[rl * 64 + ((cc ^ (rl & 7)) << 3) + lo] = f2h(o);
              }
            }
          }
#pragma unroll
          for (int it = 0; it < 4; ++it) {
            int rl = it * 8 + frow;
            uint4 vv = *(const uint4*)((const char*)wh + rl * 128 + ((fch ^ (rl & 7)) << 4));
            size_t gr = grow0 + mp * 32 + rl;
            if (gr < (size_t)M)
              *(uint4*)(C16 + gr * N + gcol0 + fch * 8) = vv;
          }
        }
      } else {
        // plain f16 (+bias): outmode 0 and V tiles of outmode 3; 4 chunks of 32 rows
#pragma unroll
        for (int mp = 0; mp < 4; ++mp) {
#pragma unroll
          for (int mi = 0; mi < 2; ++mi) {
            const int mt = mp * 2 + mi;
#pragma unroll
            for (int nt = 0; nt < 4; ++nt) {
              int col = nt * 16 + l15;
              int cc = col >> 3, lo = col & 7;
#pragma unroll
              for (int rg = 0; rg < 4; ++rg) {
                int rl = mi * 16 + quad * 4 + rg;
                wh[rl * 64 + ((cc ^ (rl & 7)) << 3) + lo] = f2h(acc[mt][nt][rg] + bl[nt]);
              }
            }
          }
#pragma unroll
          for (int it = 0; it < 4; ++it) {
            int rl = it * 8 + frow;
            uint4 vv = *(const uint4*)((const char*)wh + rl * 128 + ((fch ^ (rl & 7)) << 4));
            size_t gr = grow0 + mp * 32 + rl;
            if (gr < (size_t)M)
              *(uint4*)(C16 + gr * N + gcol0 + fch * 8) = vv;
          }
        }
      }
    }

    if (c + 1 < cpb) {
      bSp = bSpN;
      WAITV(4);   // pre-staged A0/B0/A1 confirmed (epilogue vmem is newer)
      BAR();
    }
  }
}

// ---------------------------------------------------------------- spatial attention (prep'd inputs)
__global__ __launch_bounds__(256) void attn_spatial(
    const unsigned short* __restrict__ qkv, unsigned short* __restrict__ aout) {
  __shared__ __align__(16) unsigned short sh[30720]; // 61440 B
  unsigned short* Kls = sh;          // 128 rows x 64 halves (128B rows, chunk-swizzled)
  unsigned short* Vt = sh + 8192;    // 64 x 224 halves
  unsigned short* P = sh + 22528;    // 4 waves x 2048 halves
  const int tid = threadIdx.x;
  const int w = tid >> 6, lane = tid & 63;
  const int l15 = lane & 15, quad = lane >> 4;
  const int n = blockIdx.x >> 4, h = blockIdx.x & 15;
  const size_t tb = (size_t)n * 220;
  const unsigned short* qbase = qkv + tb * 3072 + h * 64;

  f16x8 aq[4][2];
#pragma unroll
  for (int mt = 0; mt < 4; ++mt) {
    int row = w * 64 + mt * 16 + l15;
    if (row > 219) row = 219;
#pragma unroll
    for (int c = 0; c < 2; ++c)
      aq[mt][c] = *(const f16x8a*)(qbase + (size_t)row * 3072 + c * 32 + quad * 8);
  }
  if (tid < 220) {
    const uint4* src = (const uint4*)(qbase + (size_t)tid * 3072 + 2048);
    uint4 vv[8];
#pragma unroll
    for (int c = 0; c < 8; ++c) vv[c] = src[c];
    const unsigned short* us = (const unsigned short*)vv;
#pragma unroll
    for (int d = 0; d < 64; ++d) Vt[d * 224 + tid] = us[d];
  } else if (tid < 224) {
#pragma unroll
    for (int d = 0; d < 64; ++d) Vt[d * 224 + tid] = 0;
  }

  float lsum[4][4];
  f32x4 o[4][4];
#pragma unroll
  for (int mt = 0; mt < 4; ++mt)
#pragma unroll
    for (int rg = 0; rg < 4; ++rg) lsum[mt][rg] = 0.f;
#pragma unroll
  for (int mt = 0; mt < 4; ++mt)
#pragma unroll
    for (int nt = 0; nt < 4; ++nt) o[mt][nt] = (f32x4){0.f, 0.f, 0.f, 0.f};

  const int xr = (l15 & 3) ^ ((l15 >> 2) & 3);
  unsigned short* Pw = P + w * 2048;

  for (int half = 0; half < 2; ++half) {
    const int k0 = half * 128;
    const int nslot = half ? 736 : 1024;
#pragma unroll
    for (int k = 0; k < 4; ++k) {
      int slot = k * 256 + tid;
      if (slot < nslot) {
        int rl = slot >> 3, c = slot & 7;
        gll16(qbase + (size_t)(k0 + rl) * 3072 + 1024 + ((c ^ (rl & 7)) * 8),
              (char*)Kls + k * 4096 + w * 1024);
      }
    }
    __syncthreads();
    const int nci = half ? 3 : 4;
    for (int ci = 0; ci < nci; ++ci) {
      const int cig = half * 4 + ci;
      f16x8 bk[2][2];
#pragma unroll
      for (int ct = 0; ct < 2; ++ct) {
        int rl = ci * 32 + ct * 16 + l15;
#pragma unroll
        for (int c = 0; c < 2; ++c)
          bk[ct][c] = *(const f16x8a*)((const char*)Kls + rl * 128 + (((quad + 4 * c) ^ (rl & 7)) * 16));
      }
      f32x4 sc[4][2];
#pragma unroll
      for (int mt = 0; mt < 4; ++mt)
#pragma unroll
        for (int ct = 0; ct < 2; ++ct) {
          f32x4 z = (f32x4){0.f, 0.f, 0.f, 0.f};
          z = __builtin_amdgcn_mfma_f32_16x16x32_f16(aq[mt][0], bk[ct][0], z, 0, 0, 0);
          sc[mt][ct] = __builtin_amdgcn_mfma_f32_16x16x32_f16(aq[mt][1], bk[ct][1], z, 0, 0, 0);
        }
      const int okk = (cig * 32 + 16 + l15) < 220;
#pragma unroll
      for (int mt = 0; mt < 4; ++mt)
#pragma unroll
        for (int rg = 0; rg < 4; ++rg) {
          float p0 = exp2f(sc[mt][0][rg]);
          float p1 = okk ? exp2f(sc[mt][1][rg]) : 0.0f;
          lsum[mt][rg] += p0 + p1;
          int xw = quad ^ rg;
          unsigned short* pb = Pw + (mt * 16 + quad * 4 + rg) * 32;
          pb[(((l15 >> 3) ^ xw) * 8) + (l15 & 7)] = f2h(p0);
          pb[(((2 + (l15 >> 3)) ^ xw) * 8) + (l15 & 7)] = f2h(p1);
        }
      __asm__ volatile("s_waitcnt lgkmcnt(0)" ::: "memory");
      f16x8 ap[4], bv[4];
#pragma unroll
      for (int mt = 0; mt < 4; ++mt)
        ap[mt] = *(const f16x8a*)((const char*)Pw + (mt * 16 + l15) * 64 + (quad ^ xr) * 16);
#pragma unroll
      for (int nt = 0; nt < 4; ++nt)
        bv[nt] = *(const f16x8a*)((const char*)Vt + (nt * 16 + l15) * 448 + cig * 64 + quad * 16);
#pragma unroll
      for (int mt = 0; mt < 4; ++mt)
#pragma unroll
        for (int nt = 0; nt < 4; ++nt)
          o[mt][nt] = __builtin_amdgcn_mfma_f32_16x16x32_f16(ap[mt], bv[nt], o[mt][nt], 0, 0, 0);
    }
    __syncthreads();
  }

#pragma unroll
  for (int mt = 0; mt < 4; ++mt)
#pragma unroll
    for (int rg = 0; rg < 4; ++rg) {
      float l = lsum[mt][rg];
      l += __shfl_xor(l, 1);
      l += __shfl_xor(l, 2);
      l += __shfl_xor(l, 4);
      l += __shfl_xor(l, 8);
      int s = w * 64 + mt * 16 + quad * 4 + rg;
      if (s < 220) {
        float inv = 1.0f / l;
        unsigned short* dst = aout + (tb + s) * 1024 + h * 64;
#pragma unroll
        for (int nt = 0; nt < 4; ++nt) dst[nt * 16 + l15] = f2h(o[mt][nt][rg] * inv);
      }
    }
}

// ---------------------------------------------------------------- temporal attention (prep'd inputs)
__global__ __launch_bounds__(256) void attn_temporal(
    const unsigned short* __restrict__ qkv, unsigned short* __restrict__ aout) {
  __shared__ __align__(16) unsigned short sh[14336];
  const int tid = threadIdx.x;
  const int w = tid >> 6, lane = tid & 63;
  const int l15 = lane & 15, quad = lane >> 4;
  const int b = blockIdx.x / 880;
  const int rem = blockIdx.x % 880;
  const int p = rem >> 2, hq = rem & 3;
  const int h = hq * 4 + w;
  unsigned short* Vtw = sh + w * 2560;
  unsigned short* Pw = sh + 10240 + w * 1024;
  const unsigned short* base = qkv + ((size_t)(b * 24) * 220 + p) * 3072 + h * 64;
  const size_t fs = (size_t)220 * 3072;

  {
    int r = lane >> 1, hf = lane & 1;
    if (r < 24) {
      const uint4* src = (const uint4*)(base + r * fs + 2048 + hf * 32);
      uint4 vv[4];
#pragma unroll
      for (int c = 0; c < 4; ++c) vv[c] = src[c];
      const unsigned short* us = (const unsigned short*)vv;
#pragma unroll
      for (int j = 0; j < 32; ++j) Vtw[(hf * 32 + j) * 40 + r] = us[j];
    } else {
#pragma unroll
      for (int j = 0; j < 32; ++j) Vtw[(hf * 32 + j) * 40 + r] = 0;
    }
  }
  f16x8 aq[2][2], bk[2][2];
#pragma unroll
  for (int mt = 0; mt < 2; ++mt) {
    int row = mt * 16 + l15;
    if (row > 23) row = 23;
#pragma unroll
    for (int c = 0; c < 2; ++c)
      aq[mt][c] = *(const f16x8a*)(base + row * fs + c * 32 + quad * 8);
  }
#pragma unroll
  for (int ct = 0; ct < 2; ++ct) {
    int row = ct * 16 + l15;
    if (row > 23) row = 23;
#pragma unroll
    for (int c = 0; c < 2; ++c)
      bk[ct][c] = *(const f16x8a*)(base + row * fs + 1024 + c * 32 + quad * 8);
  }
  f32x4 sc[2][2];
#pragma unroll
  for (int mt = 0; mt < 2; ++mt)
#pragma unroll
    for (int ct = 0; ct < 2; ++ct) {
      f32x4 z = (f32x4){0.f, 0.f, 0.f, 0.f};
      z = __builtin_amdgcn_mfma_f32_16x16x32_f16(aq[mt][0], bk[ct][0], z, 0, 0, 0);
      sc[mt][ct] = __builtin_amdgcn_mfma_f32_16x16x32_f16(aq[mt][1], bk[ct][1], z, 0, 0, 0);
    }
  const int xr = (l15 & 3) ^ ((l15 >> 2) & 3);
  const int okk = l15 < 8;
  float lr[2][4];
#pragma unroll
  for (int mt = 0; mt < 2; ++mt)
#pragma unroll
    for (int rg = 0; rg < 4; ++rg) {
      float p0 = exp2f(sc[mt][0][rg]);
      float p1 = okk ? exp2f(sc[mt][1][rg]) : 0.0f;
      float rs = p0 + p1;
      rs += __shfl_xor(rs, 1);
      rs += __shfl_xor(rs, 2);
      rs += __shfl_xor(rs, 4);
      rs += __shfl_xor(rs, 8);
      lr[mt][rg] = rs;
      int xw = quad ^ rg;
      unsigned short* pb = Pw + (mt * 16 + quad * 4 + rg) * 32;
      pb[(((l15 >> 3) ^ xw) * 8) + (l15 & 7)] = f2h(p0);
      pb[(((2 + (l15 >> 3)) ^ xw) * 8) + (l15 & 7)] = f2h(p1);
    }
  __asm__ volatile("s_waitcnt lgkmcnt(0)" ::: "memory");
  f16x8 ap[2], bv[4];
#pragma unroll
  for (int mt = 0; mt < 2; ++mt)
    ap[mt] = *(const f16x8a*)((const char*)Pw + (mt * 16 + l15) * 64 + (quad ^ xr) * 16);
#pragma unroll
  for (int nt = 0; nt < 4; ++nt)
    bv[nt] = *(const f16x8a*)((const char*)Vtw + (nt * 16 + l15) * 80 + quad * 16);
  f32x4 o[2][4];
#pragma unroll
  for (int mt = 0; mt < 2; ++mt)
#pragma unroll
    for (int nt = 0; nt < 4; ++nt) {
      f32x4 z = (f32x4){0.f, 0.f, 0.f, 0.f};
      o[mt][nt] = __builtin_amdgcn_mfma_f32_16x16x32_f16(ap[mt], bv[nt], z, 0, 0, 0);
    }
#pragma unroll
  for (int mt = 0; mt < 2; ++mt)
#pragma unroll
    for (int rg = 0; rg < 4; ++rg) {
      int s = mt * 16 + quad * 4 + rg;
      if (s < 24) {
        float inv = 1.0f / lr[mt][rg];
        unsigned short* dst = aout + ((size_t)(b * 24 + s) * 220 + p) * 1024 + h * 64;
#pragma unroll
        for (int nt = 0; nt < 4; ++nt) dst[nt * 16 + l15] = f2h(o[mt][nt][rg] * inv);
      }
    }
}

// ---------------------------------------------------------------- launch
extern "C" void kernel_launch(void* const* d_in, const int* in_sizes, int n_in,
                              void* d_out, int out_size, void* d_ws, size_t ws_size,
                              hipStream_t stream) {
  (void)in_sizes; (void)n_in; (void)out_size; (void)ws_size;
  const float* x = (const float*)d_in[0];
  const float* wsqkv = (const float*)d_in[1];
  const float* wsproj = (const float*)d_in[2];
  const float* bsproj = (const float*)d_in[3];
  const float* wtqkv = (const float*)d_in[4];
  const float* wtproj = (const float*)d_in[5];
  const float* btproj = (const float*)d_in[6];
  const float* sqg = (const float*)d_in[7];
  const float* skg = (const float*)d_in[8];
  const float* tqg = (const float*)d_in[9];
  const float* tkg = (const float*)d_in[10];

  static bool attr_done = false;
  if (!attr_done) {
    hipFuncSetAttribute(reinterpret_cast<const void*>(gemm256),
                        hipFuncAttributeMaxDynamicSharedMemorySize, 163840);
    attr_done = true;
  }

  char* ws = (char*)d_ws;
  size_t off = 0;
  auto alloc = [&](size_t bytes) {
    char* ptr = ws + off;
    off += (bytes + 255) & ~(size_t)255;
    return ptr;
  };
  unsigned short* xb = (unsigned short*)alloc((size_t)MPAD * 1024 * 2);
  unsigned short* qkvb = (unsigned short*)alloc((size_t)NTOK * 3072 * 2);
  unsigned short* aoutb = (unsigned short*)alloc((size_t)MPAD * 1024 * 2);
  unsigned short* wsqkvb = (unsigned short*)alloc((size_t)3072 * 1024 * 2);
  unsigned short* wsprojTb = (unsigned short*)alloc((size_t)1024 * 1024 * 2);
  unsigned short* wtqkvb = (unsigned short*)alloc((size_t)3072 * 1024 * 2);
  unsigned short* wtprojb = (unsigned short*)alloc((size_t)1024 * 1024 * 2);
  unsigned short* wcb = (unsigned short*)alloc((size_t)3072 * 1024 * 2);
  float* bcb = (float*)alloc(3072 * 4);
  float2* tabS = (float2*)alloc(220 * 32 * 8);
  float2* tabT = (float2*)alloc(24 * 32 * 8);

  // zero the 128 padded A-rows (read by 256-row tiles, never written by casts/attn)
  hipMemsetAsync(xb + (size_t)NTOK * 1024, 0, (size_t)(MPAD - NTOK) * 1024 * 2, stream);
  hipMemsetAsync(aoutb + (size_t)NTOK * 1024, 0, (size_t)(MPAD - NTOK) * 1024 * 2, stream);

  dim3 blk(256);
  cast_kernel<<<21120, blk, 0, stream>>>(x, xb, 5406720);
  cast_kernel<<<3072, blk, 0, stream>>>(wsqkv, wsqkvb, 786432);
  cast_kernel<<<3072, blk, 0, stream>>>(wtqkv, wtqkvb, 786432);
  cast_kernel<<<1024, blk, 0, stream>>>(wtproj, wtprojb, 262144);
  transpose_cast_kernel<<<1024, blk, 0, stream>>>(wsproj, wsprojTb);
  bias_combine_kernel<<<12, blk, 0, stream>>>(wtqkv, bsproj, bcb);
  rope_table_kernel<<<31, blk, 0, stream>>>(tabS, tabT);

  // Wc = Wtqkv * Wsproj  (so qkv_t = out_s * Wc^T + bc) — small, keep 128² kernel
  gemm_bt<<<dim3(24 * 8), blk, 0, stream>>>(wtqkvb, wsprojTb, nullptr, wcb, 3072, 1024, 1024, 0,
                                            nullptr, nullptr, nullptr, 0);

  dim3 blk512(512);
  // stage S: fused QKV + prep — persistent: 249 blocks x 4 tiles (83 tm x 12 tn)
  gemm256<<<dim3(249), blk512, 163840, stream>>>(xb, wsqkvb, nullptr, qkvb, NTOK, 3072, 1024, 3,
                                                 tabS, sqg, skg, 0, 4);
  attn_spatial<<<dim3(1536), blk, 0, stream>>>(qkvb, aoutb);
  // stage T: (proj_S ∘ QKV_T) folded into one GEMM with combined weight + bias, fused prep
  gemm256<<<dim3(249), blk512, 163840, stream>>>(aoutb, wcb, bcb, qkvb, NTOK, 3072, 1024, 3,
                                                 tabT, tqg, tkg, 1, 4);
  attn_temporal<<<dim3(3520), blk, 0, stream>>>(qkvb, aoutb);
  // final projection (83 x 4 tiles, one tile per block)
  gemm256<<<dim3(83 * 4), blk512, 163840, stream>>>(aoutb, wtprojb, btproj, (float*)d_out,
                                                    NTOK, 1024, 1024, 2,
                                                    nullptr, nullptr, nullptr, 0, 1);
}

// Round 6
// 695.267 us; speedup vs baseline: 2.0951x; 2.0951x over previous
//
#include <hip/hip_runtime.h>

typedef _Float16 f16;
typedef _Float16 f16x8 __attribute__((ext_vector_type(8)));
typedef f16x8 f16x8a __attribute__((may_alias));
typedef float f32x4 __attribute__((ext_vector_type(4)));

#define NTOK 21120          // 4 * 5280 tokens
#define MPAD 21248          // NTOK padded to 256-row tiles
#define SCALE_Q 0.18033688f // (1/8) * log2(e)

__device__ __forceinline__ void gll16(const void* g, void* l) {
  __builtin_amdgcn_global_load_lds(
      (const __attribute__((address_space(1))) unsigned int*)g,
      (__attribute__((address_space(3))) unsigned int*)l, 16, 0, 0);
}

__device__ __forceinline__ unsigned int pack2(float a, float b) {
  union { f16 h[2]; unsigned int u; } c;
  c.h[0] = (f16)a; c.h[1] = (f16)b;
  return c.u;
}
__device__ __forceinline__ unsigned short f2h(float a) {
  union { f16 h; unsigned short u; } c; c.h = (f16)a; return c.u;
}

// DPP cross-lane (VALU pipe, no DS ops). 0xB1=quad xor1, 0x4E=quad xor2,
// 0x141=row_half_mirror, 0x140=row_mirror
template <int C>
__device__ __forceinline__ float dppf(float x) {
  union { float f; int i; } u, r;
  u.f = x;
  r.i = __builtin_amdgcn_update_dpp(0, u.i, C, 0xf, 0xf, true);
  return r.f;
}

// ---------------------------------------------------------------- casts
__global__ __launch_bounds__(256) void cast_kernel(
    const float* __restrict__ in, unsigned short* __restrict__ out, int n4) {
  int i = blockIdx.x * 256 + threadIdx.x;
  if (i >= n4) return;
  float4 v = ((const float4*)in)[i];
  uint2 o;
  o.x = pack2(v.x, v.y);
  o.y = pack2(v.z, v.w);
  ((uint2*)out)[i] = o;
}

// transpose + cast 1024x1024 f32 -> f16 (out[d][c] = in[c][d])
__global__ __launch_bounds__(256) void transpose_cast_kernel(
    const float* __restrict__ in, unsigned short* __restrict__ out) {
  __shared__ float tile[32][33];
  int bx = blockIdx.x & 31, by = blockIdx.x >> 5;
  int tx = threadIdx.x & 31, ty = threadIdx.x >> 5;
#pragma unroll
  for (int i = 0; i < 32; i += 8)
    tile[ty + i][tx] = in[(size_t)(by * 32 + ty + i) * 1024 + bx * 32 + tx];
  __syncthreads();
#pragma unroll
  for (int i = 0; i < 32; i += 8)
    out[(size_t)(bx * 32 + ty + i) * 1024 + by * 32 + tx] = f2h(tile[tx][ty + i]);
}

// bc[e] = sum_c wtqkv[e][c] * bsproj[c]   (e in [0,3072))
// 192 blocks x 16 e-rows, 16 threads per row + shfl reduce (was 12 blocks,
// 1 thread/row -> only 12 CUs active, latency-bound on 12 MB of weight reads)
__global__ __launch_bounds__(256) void bias_combine_kernel(
    const float* __restrict__ w, const float* __restrict__ b, float* __restrict__ bc) {
  int e = blockIdx.x * 16 + (threadIdx.x >> 4);
  int sub = threadIdx.x & 15;
  const float4* wr = (const float4*)(w + (size_t)e * 1024);
  const float4* b4 = (const float4*)b;
  float s = 0.f;
  for (int c = sub; c < 256; c += 16) {
    float4 wv = wr[c], bv = b4[c];
    s += wv.x * bv.x + wv.y * bv.y + wv.z * bv.z + wv.w * bv.w;
  }
  s += __shfl_xor(s, 1);
  s += __shfl_xor(s, 2);
  s += __shfl_xor(s, 4);
  s += __shfl_xor(s, 8);
  if (sub == 0) bc[e] = s;
}

// ---------------------------------------------------------------- rope tables
__global__ __launch_bounds__(256) void rope_table_kernel(float2* tabS, float2* tabT) {
  int t = blockIdx.x * 256 + threadIdx.x;
  const float lb = logf(10000.0f) * (1.0f / 32.0f);
  if (t < 220 * 32) {
    int s = t >> 5, i = t & 31;
    float theta = expf(-(float)i * lb);
    float ang = (float)s * theta;
    tabS[t] = make_float2(cosf(ang), sinf(ang));
  } else if (t < 220 * 32 + 24 * 32) {
    int u = t - 220 * 32;
    int s = u >> 5, i = u & 31;
    float theta = expf(-(float)i * lb);
    float ang = (float)s * theta;
    tabT[u] = make_float2(cosf(ang), sinf(ang));
  }
}

// ---------------------------------------------------------------- small GEMM (kept for Wc)
__global__ __launch_bounds__(256) void gemm_bt(
    const unsigned short* __restrict__ A, const unsigned short* __restrict__ B,
    const float* __restrict__ bias, void* __restrict__ C,
    int M, int N, int K, int outmode,
    const float2* __restrict__ tab, const float* __restrict__ gq,
    const float* __restrict__ gk, int mode) {
  __shared__ __align__(16) unsigned short sh[16384];
  unsigned short* As = sh;
  unsigned short* Bs = sh + 8192;
  const int tid = threadIdx.x;
  const int w = tid >> 6, lane = tid & 63;
  const int l15 = lane & 15, quad = lane >> 4;
  const int wr = w >> 1, wc = w & 1;

  const int ntn = N >> 7;
  const int stride = ntn << 3;
  const int g = blockIdx.x / stride, r = blockIdx.x % stride;
  const int tn = r % ntn, tm = g * 8 + r / ntn;

  f32x4 acc[4][4];
#pragma unroll
  for (int a = 0; a < 4; ++a)
#pragma unroll
    for (int b = 0; b < 4; ++b) acc[a][b] = (f32x4){0.f, 0.f, 0.f, 0.f};

  const int srow = tid >> 3;
  const int schk = tid & 7;
  const size_t arow0 = (size_t)tm * 128;
  const size_t brow0 = (size_t)tn * 128;
  const int nk = K >> 6;

  for (int kt = 0; kt < nk; ++kt) {
    __syncthreads();
    const int kb = kt << 6;
#pragma unroll
    for (int rd = 0; rd < 4; ++rd) {
      int row = rd * 32 + srow;
      int sc = (schk ^ (row & 7)) * 8;
      gll16(A + (arow0 + row) * K + kb + sc, (char*)As + rd * 4096 + tid * 16);
      gll16(B + (brow0 + row) * K + kb + sc, (char*)Bs + rd * 4096 + tid * 16);
    }
    __syncthreads();
#pragma unroll
    for (int kk = 0; kk < 2; ++kk) {
      f16x8 af[4], bf[4];
#pragma unroll
      for (int mt = 0; mt < 4; ++mt) {
        int ra = wr * 64 + mt * 16 + l15;
        af[mt] = *(const f16x8a*)((const char*)As + ra * 128 + (((kk * 4 + quad) ^ (ra & 7)) * 16));
        int rb = wc * 64 + mt * 16 + l15;
        bf[mt] = *(const f16x8a*)((const char*)Bs + rb * 128 + (((kk * 4 + quad) ^ (rb & 7)) * 16));
      }
#pragma unroll
      for (int mt = 0; mt < 4; ++mt)
#pragma unroll
        for (int nt = 0; nt < 4; ++nt)
          acc[mt][nt] = __builtin_amdgcn_mfma_f32_16x16x32_f16(af[mt], bf[nt], acc[mt][nt], 0, 0, 0);
    }
  }

  // f16 epilogue: 2 passes through LDS (64 x 128, stride 136)
  unsigned short* Cs = (unsigned short*)C;
#pragma unroll
  for (int p = 0; p < 2; ++p) {
    __syncthreads();
#pragma unroll
    for (int mi = 0; mi < 2; ++mi) {
      int mt = p * 2 + mi;
      int rl = wr * 32 + mi * 16 + quad * 4;
#pragma unroll
      for (int nt = 0; nt < 4; ++nt) {
        int cl = wc * 64 + nt * 16 + l15;
#pragma unroll
        for (int rg = 0; rg < 4; ++rg)
          sh[(rl + rg) * 136 + cl] = f2h(acc[mt][nt][rg]);
      }
    }
    __syncthreads();
#pragma unroll
    for (int c = 0; c < 4; ++c) {
      int rl = c * 16 + (tid >> 4), cx = tid & 15;
      int grow = tm * 128 + ((rl >> 5) << 6) + p * 32 + (rl & 31);
      uint4 v = *(const uint4*)&sh[rl * 136 + cx * 8];
      *(uint4*)&Cs[(size_t)grow * N + tn * 128 + cx * 8] = v;
    }
  }
}

// ---------------------------------------------------------------- big GEMM: 256x256 tile
// 8 waves, per-wave 128x64 C. K=1024 hard (16 tiles of BK=64).
// LDS 160 KB: A ring = 3 tiles (32 KB each), B ring = 2 tiles.
// ONE barrier per K-tile. Within a tile, quadrants are sequenced with counted
// lgkmcnt waits (ds ops complete in order): reads of quadrant q+1 are issued
// under the MFMAs of quadrant q. vmcnt(4) once per tile confirms A(t+1)+B(t+1);
// A(t+2) stays in flight (never drain mid-loop). [Round-3 verified: 166 us,
// MfmaUtil 35%, 0 bank conflicts. Round-4 persistence REVERTED: A-refetch per
// sweep + spill tripled FETCH/WRITE.]
#define FENCE() asm volatile("" ::: "memory")
#define BAR() do { FENCE(); __builtin_amdgcn_s_barrier(); FENCE(); } while (0)
#define WAITV(N) asm volatile("s_waitcnt vmcnt(" #N ")" ::: "memory")
#define WAITL(N) do { asm volatile("s_waitcnt lgkmcnt(" #N ")" ::: "memory"); \
                      __builtin_amdgcn_sched_barrier(0); } while (0)
#define ASLOT(T) (((T) % 3) * 32768)
#define BSLOT(T) (98304 + ((T) & 1) * 32768)
#define LDAf(T, mt, kk) (*(const f16x8a*)(smem + ASLOT(T) + wrOff + (mt) * 2048 + (aoff ^ ((kk) << 6))))
#define LDBf(T, nt, kk) (*(const f16x8a*)(smem + BSLOT(T) + bcOff + (nt) * 2048 + (aoff ^ ((kk) << 6))))
#define STAGE_A2(T, h) do { \
    gll16(aSp + (size_t)((h) * 128) * K + (T) * 64, smem + ASLOT(T) + (h) * 16384 + tid * 16); \
    gll16(aSp + (size_t)((h) * 128 + 64) * K + (T) * 64, smem + ASLOT(T) + (h) * 16384 + 8192 + tid * 16); \
  } while (0)
#define STAGE_B2(T, h) do { \
    gll16(bSp + (size_t)((h) * 128) * K + (T) * 64, smem + BSLOT(T) + (h) * 16384 + tid * 16); \
    gll16(bSp + (size_t)((h) * 128 + 64) * K + (T) * 64, smem + BSLOT(T) + (h) * 16384 + 8192 + tid * 16); \
  } while (0)
#define MM16(QB, A0_, A1_, A2_, A3_, B0_, B1_, B2_, B3_) do { \
    acc[QB + 0][0] = __builtin_amdgcn_mfma_f32_16x16x32_f16(A0_, B0_, acc[QB + 0][0], 0, 0, 0); \
    acc[QB + 0][1] = __builtin_amdgcn_mfma_f32_16x16x32_f16(A0_, B1_, acc[QB + 0][1], 0, 0, 0); \
    acc[QB + 0][2] = __builtin_amdgcn_mfma_f32_16x16x32_f16(A0_, B2_, acc[QB + 0][2], 0, 0, 0); \
    acc[QB + 0][3] = __builtin_amdgcn_mfma_f32_16x16x32_f16(A0_, B3_, acc[QB + 0][3], 0, 0, 0); \
    acc[QB + 1][0] = __builtin_amdgcn_mfma_f32_16x16x32_f16(A1_, B0_, acc[QB + 1][0], 0, 0, 0); \
    acc[QB + 1][1] = __builtin_amdgcn_mfma_f32_16x16x32_f16(A1_, B1_, acc[QB + 1][1], 0, 0, 0); \
    acc[QB + 1][2] = __builtin_amdgcn_mfma_f32_16x16x32_f16(A1_, B2_, acc[QB + 1][2], 0, 0, 0); \
    acc[QB + 1][3] = __builtin_amdgcn_mfma_f32_16x16x32_f16(A1_, B3_, acc[QB + 1][3], 0, 0, 0); \
    acc[QB + 2][0] = __builtin_amdgcn_mfma_f32_16x16x32_f16(A2_, B0_, acc[QB + 2][0], 0, 0, 0); \
    acc[QB + 2][1] = __builtin_amdgcn_mfma_f32_16x16x32_f16(A2_, B1_, acc[QB + 2][1], 0, 0, 0); \
    acc[QB + 2][2] = __builtin_amdgcn_mfma_f32_16x16x32_f16(A2_, B2_, acc[QB + 2][2], 0, 0, 0); \
    acc[QB + 2][3] = __builtin_amdgcn_mfma_f32_16x16x32_f16(A2_, B3_, acc[QB + 2][3], 0, 0, 0); \
    acc[QB + 3][0] = __builtin_amdgcn_mfma_f32_16x16x32_f16(A3_, B0_, acc[QB + 3][0], 0, 0, 0); \
    acc[QB + 3][1] = __builtin_amdgcn_mfma_f32_16x16x32_f16(A3_, B1_, acc[QB + 3][1], 0, 0, 0); \
    acc[QB + 3][2] = __builtin_amdgcn_mfma_f32_16x16x32_f16(A3_, B2_, acc[QB + 3][2], 0, 0, 0); \
    acc[QB + 3][3] = __builtin_amdgcn_mfma_f32_16x16x32_f16(A3_, B3_, acc[QB + 3][3], 0, 0, 0); \
  } while (0)

__global__ __launch_bounds__(512, 2) void gemm256(
    const unsigned short* __restrict__ A, const unsigned short* __restrict__ B,
    const float* __restrict__ bias, void* __restrict__ C,
    int M, int N, int K, int outmode,
    const float2* __restrict__ tab, const float* __restrict__ gq,
    const float* __restrict__ gk, int mode) {
  extern __shared__ char smem[];
  const int tid = threadIdx.x;
  const int w = tid >> 6, lane = tid & 63;
  const int l15 = lane & 15, quad = lane >> 4;
  const int wr = w >> 2, wc = w & 3;

  // XCD-bijective swizzle (nwg % 8 != 0 safe) + 8-row supertiles
  const int nwg = gridDim.x;
  const int qd = nwg >> 3, rm = nwg & 7;
  const int xcd = blockIdx.x & 7, lin = blockIdx.x >> 3;
  const int wgid = (xcd < rm ? xcd * (qd + 1) : rm * (qd + 1) + (xcd - rm) * qd) + lin;
  const int ntn = N >> 8;
  const int stg = ntn << 3;
  const int g = wgid / stg, r2 = wgid % stg;
  const int tn = r2 % ntn, tm = g * 8 + r2 / ntn;

  const int wrOff = wr * 16384;
  const int bcOff = (wc >> 1) * 16384 + (wc & 1) * 8192;
  const int aoff = l15 * 128 + ((quad ^ (l15 & 7)) << 4);

  // staging source (pre-swizzled column so LDS dest stays lane-linear)
  const int sc = ((tid & 7) ^ ((tid >> 3) & 7)) * 8;
  const unsigned short* aSp = A + (size_t)(tm * 256 + (tid >> 3)) * K + sc;
  const unsigned short* bSp = B + (size_t)(tn * 256 + (tid >> 3)) * K + sc;

  f32x4 acc[8][4];
#pragma unroll
  for (int i = 0; i < 8; ++i)
#pragma unroll
    for (int j = 0; j < 4; ++j) acc[i][j] = (f32x4){0.f, 0.f, 0.f, 0.f};

  // prologue: A[0], B[0], A[1]; vmcnt(4) -> A0,B0 confirmed, A1 in flight
  STAGE_A2(0, 0); STAGE_A2(0, 1);
  STAGE_B2(0, 0); STAGE_B2(0, 1);
  STAGE_A2(1, 0); STAGE_A2(1, 1);
  WAITV(4);
  BAR();

#pragma unroll
  for (int t = 0; t < 16; ++t) {
    f16x8 bA0, bA1, bA2, bA3, bB0, bB1, bB2, bB3;
    f16x8 aA0, aA1, aA2, aA3, aB0, aB1, aB2, aB3;
    f16x8 aC0, aC1, aC2, aC3, aD0, aD1, aD2, aD3;
    // R0 (8 ds): B k0 + A rows0-3 k0
    bA0 = LDBf(t, 0, 0); bA1 = LDBf(t, 1, 0); bA2 = LDBf(t, 2, 0); bA3 = LDBf(t, 3, 0);
    aA0 = LDAf(t, 0, 0); aA1 = LDAf(t, 1, 0); aA2 = LDAf(t, 2, 0); aA3 = LDAf(t, 3, 0);
    // R1 (4 ds): A rows4-7 k0
    aB0 = LDAf(t, 4, 0); aB1 = LDAf(t, 5, 0); aB2 = LDAf(t, 6, 0); aB3 = LDAf(t, 7, 0);
    if (t <= 14) { STAGE_B2(t + 1, 0); STAGE_B2(t + 1, 1); }
    WAITL(4);                                   // R0 done, R1 may fly
    __builtin_amdgcn_s_setprio(1);
    MM16(0, aA0, aA1, aA2, aA3, bA0, bA1, bA2, bA3);
    __builtin_amdgcn_s_setprio(0);
    // R2 (8 ds): B k1 + A rows0-3 k1 (overlaps Q0/Q1 MFMAs)
    bB0 = LDBf(t, 0, 1); bB1 = LDBf(t, 1, 1); bB2 = LDBf(t, 2, 1); bB3 = LDBf(t, 3, 1);
    aC0 = LDAf(t, 0, 1); aC1 = LDAf(t, 1, 1); aC2 = LDAf(t, 2, 1); aC3 = LDAf(t, 3, 1);
    WAITL(8);                                   // R1 done, R2 may fly
    __builtin_amdgcn_s_setprio(1);
    MM16(4, aB0, aB1, aB2, aB3, bA0, bA1, bA2, bA3);
    __builtin_amdgcn_s_setprio(0);
    // R3 (4 ds): A rows4-7 k1
    aD0 = LDAf(t, 4, 1); aD1 = LDAf(t, 5, 1); aD2 = LDAf(t, 6, 1); aD3 = LDAf(t, 7, 1);
    if (t <= 13) { STAGE_A2(t + 2, 0); STAGE_A2(t + 2, 1); }
    WAITL(4);                                   // R2 done, R3 may fly
    __builtin_amdgcn_s_setprio(1);
    MM16(0, aC0, aC1, aC2, aC3, bB0, bB1, bB2, bB3);
    __builtin_amdgcn_s_setprio(0);
    WAITL(0);                                   // R3 done
    __builtin_amdgcn_s_setprio(1);
    MM16(4, aD0, aD1, aD2, aD3, bB0, bB1, bB2, bB3);
    __builtin_amdgcn_s_setprio(0);
    if (t <= 13) { WAITV(4); } else if (t == 14) { WAITV(0); }
    BAR();                                      // the only barrier per K-tile
  }

  // ---------------- epilogue: per-wave private 16KB LDS region, no further barriers
  const size_t grow0 = (size_t)tm * 256 + wr * 128;
  const int gcol0 = tn * 256 + wc * 64;

  float bl[4] = {0.f, 0.f, 0.f, 0.f};
  if (bias != nullptr) {
#pragma unroll
    for (int nt = 0; nt < 4; ++nt) bl[nt] = bias[gcol0 + nt * 16 + l15];
  }

  if (outmode == 2) {
    // f32 + bias, two 64-row halves (16KB region each pass)
    float* wf = (float*)(smem + w * 16384);
    const int frow = lane >> 4, fc = lane & 15;
#pragma unroll
    for (int h = 0; h < 2; ++h) {
#pragma unroll
      for (int mi = 0; mi < 4; ++mi)
#pragma unroll
        for (int nt = 0; nt < 4; ++nt)
#pragma unroll
          for (int rg = 0; rg < 4; ++rg) {
            int row = mi * 16 + quad * 4 + rg;
            int col = nt * 16 + l15;
            int c = col >> 2, lo = col & 3;
            wf[row * 64 + ((c ^ (row & 15)) << 2) + lo] = acc[h * 4 + mi][nt][rg] + bl[nt];
          }
#pragma unroll
      for (int it = 0; it < 16; ++it) {
        int row = it * 4 + frow;
        float4 v = *(const float4*)(wf + row * 64 + ((fc ^ (row & 15)) << 2));
        size_t gr = grow0 + h * 64 + row;
        if (gr < (size_t)M)
          *(float4*)((float*)C + gr * N + gcol0 + fc * 4) = v;
      }
    }
    return;
  }

  unsigned short* wh = (unsigned short*)(smem + w * 16384);
  if (outmode == 3 && tn < 8) {
    // fused RMSNorm + gain + RoPE: one head (64 cols) per wave, all in registers
    const int isQ = tn < 4;
    const float* gg = isQ ? gq : gk;
    float gv[4];
#pragma unroll
    for (int nt = 0; nt < 4; ++nt) gv[nt] = gg[nt * 16 + l15];
#pragma unroll
    for (int mt = 0; mt < 8; ++mt) {
      float v[4][4], rr[4];
#pragma unroll
      for (int rg = 0; rg < 4; ++rg) rr[rg] = 0.f;
#pragma unroll
      for (int nt = 0; nt < 4; ++nt)
#pragma unroll
        for (int rg = 0; rg < 4; ++rg) {
          float x = acc[mt][nt][rg] + bl[nt];
          v[nt][rg] = x;
          rr[rg] += x * x;
        }
#pragma unroll
      for (int rg = 0; rg < 4; ++rg) {
        float s = rr[rg];
        s += dppf<0xB1>(s);   // 16-lane butterfly sum, VALU-only
        s += dppf<0x4E>(s);
        s += dppf<0x141>(s);
        s += dppf<0x140>(s);
        float r = rsqrtf(s * (1.0f / 64.0f) + 1e-6f);
        rr[rg] = isQ ? r * SCALE_Q : r;
      }
      int pos[4];
#pragma unroll
      for (int rg = 0; rg < 4; ++rg) {
        int grow = (int)grow0 + mt * 16 + quad * 4 + rg;
        pos[rg] = mode ? ((grow / 220) % 24) : (grow % 220);
      }
#pragma unroll
      for (int nt = 0; nt < 4; ++nt) {
        int col = nt * 16 + l15;
        int ii = nt * 8 + (l15 >> 1);
        int c = col >> 3, lo = col & 7;
#pragma unroll
        for (int rg = 0; rg < 4; ++rg) {
          float2 cs = tab[pos[rg] * 32 + ii];
          float x = v[nt][rg] * rr[rg] * gv[nt];
          float p = dppf<0xB1>(x);  // pair partner (adjacent lane)
          float o = (l15 & 1) ? (x * cs.x + p * cs.y) : (x * cs.x - p * cs.y);
          int row = mt * 16 + quad * 4 + rg;
          wh[row * 64 + ((c ^ (row & 7)) << 3) + lo] = f2h(o);
        }
      }
    }
  } else {
    // plain f16 (+bias): outmode 0 and V tiles of outmode 3
#pragma unroll
    for (int mt = 0; mt < 8; ++mt)
#pragma unroll
      for (int nt = 0; nt < 4; ++nt) {
        int col = nt * 16 + l15;
        int c = col >> 3, lo = col & 7;
#pragma unroll
        for (int rg = 0; rg < 4; ++rg) {
          int row = mt * 16 + quad * 4 + rg;
          wh[row * 64 + ((c ^ (row & 7)) << 3) + lo] = f2h(acc[mt][nt][rg] + bl[nt]);
        }
      }
  }
  // coalesced flush: 128 rows x 128B, 8 lanes per row
  {
    const int frow = lane >> 3, fch = lane & 7;
    unsigned short* C16 = (unsigned short*)C;
#pragma unroll
    for (int it = 0; it < 16; ++it) {
      int row = it * 8 + frow;
      uint4 vv = *(const uint4*)((const char*)wh + row * 128 + ((fch ^ (row & 7)) << 4));
      size_t gr = grow0 + row;
      if (gr < (size_t)M)
        *(uint4*)(C16 + gr * N + gcol0 + fch * 8) = vv;
    }
  }
}

// ---------------------------------------------------------------- spatial attention (prep'd inputs)
__global__ __launch_bounds__(256) void attn_spatial(
    const unsigned short* __restrict__ qkv, unsigned short* __restrict__ aout) {
  __shared__ __align__(16) unsigned short sh[30720]; // 61440 B
  unsigned short* Kls = sh;          // 128 rows x 64 halves (128B rows, chunk-swizzled)
  unsigned short* Vt = sh + 8192;    // 64 x 224 halves
  unsigned short* P = sh + 22528;    // 4 waves x 2048 halves
  const int tid = threadIdx.x;
  const int w = tid >> 6, lane = tid & 63;
  const int l15 = lane & 15, quad = lane >> 4;
  const int n = blockIdx.x >> 4, h = blockIdx.x & 15;
  const size_t tb = (size_t)n * 220;
  const unsigned short* qbase = qkv + tb * 3072 + h * 64;

  f16x8 aq[4][2];
#pragma unroll
  for (int mt = 0; mt < 4; ++mt) {
    int row = w * 64 + mt * 16 + l15;
    if (row > 219) row = 219;
#pragma unroll
    for (int c = 0; c < 2; ++c)
      aq[mt][c] = *(const f16x8a*)(qbase + (size_t)row * 3072 + c * 32 + quad * 8);
  }
  if (tid < 220) {
    const uint4* src = (const uint4*)(qbase + (size_t)tid * 3072 + 2048);
    uint4 vv[8];
#pragma unroll
    for (int c = 0; c < 8; ++c) vv[c] = src[c];
    const unsigned short* us = (const unsigned short*)vv;
#pragma unroll
    for (int d = 0; d < 64; ++d) Vt[d * 224 + tid] = us[d];
  } else if (tid < 224) {
#pragma unroll
    for (int d = 0; d < 64; ++d) Vt[d * 224 + tid] = 0;
  }

  float lsum[4][4];
  f32x4 o[4][4];
#pragma unroll
  for (int mt = 0; mt < 4; ++mt)
#pragma unroll
    for (int rg = 0; rg < 4; ++rg) lsum[mt][rg] = 0.f;
#pragma unroll
  for (int mt = 0; mt < 4; ++mt)
#pragma unroll
    for (int nt = 0; nt < 4; ++nt) o[mt][nt] = (f32x4){0.f, 0.f, 0.f, 0.f};

  const int xr = (l15 & 3) ^ ((l15 >> 2) & 3);
  unsigned short* Pw = P + w * 2048;

  for (int half = 0; half < 2; ++half) {
    const int k0 = half * 128;
    const int nslot = half ? 736 : 1024;
#pragma unroll
    for (int k = 0; k < 4; ++k) {
      int slot = k * 256 + tid;
      if (slot < nslot) {
        int rl = slot >> 3, c = slot & 7;
        gll16(qbase + (size_t)(k0 + rl) * 3072 + 1024 + ((c ^ (rl & 7)) * 8),
              (char*)Kls + k * 4096 + w * 1024);
      }
    }
    __syncthreads();
    const int nci = half ? 3 : 4;
    for (int ci = 0; ci < nci; ++ci) {
      const int cig = half * 4 + ci;
      f16x8 bk[2][2];
#pragma unroll
      for (int ct = 0; ct < 2; ++ct) {
        int rl = ci * 32 + ct * 16 + l15;
#pragma unroll
        for (int c = 0; c < 2; ++c)
          bk[ct][c] = *(const f16x8a*)((const char*)Kls + rl * 128 + (((quad + 4 * c) ^ (rl & 7)) * 16));
      }
      f32x4 sc[4][2];
#pragma unroll
      for (int mt = 0; mt < 4; ++mt)
#pragma unroll
        for (int ct = 0; ct < 2; ++ct) {
          f32x4 z = (f32x4){0.f, 0.f, 0.f, 0.f};
          z = __builtin_amdgcn_mfma_f32_16x16x32_f16(aq[mt][0], bk[ct][0], z, 0, 0, 0);
          sc[mt][ct] = __builtin_amdgcn_mfma_f32_16x16x32_f16(aq[mt][1], bk[ct][1], z, 0, 0, 0);
        }
      const int okk = (cig * 32 + 16 + l15) < 220;
#pragma unroll
      for (int mt = 0; mt < 4; ++mt)
#pragma unroll
        for (int rg = 0; rg < 4; ++rg) {
          float p0 = exp2f(sc[mt][0][rg]);
          float p1 = okk ? exp2f(sc[mt][1][rg]) : 0.0f;
          lsum[mt][rg] += p0 + p1;
          int xw = quad ^ rg;
          unsigned short* pb = Pw + (mt * 16 + quad * 4 + rg) * 32;
          pb[(((l15 >> 3) ^ xw) * 8) + (l15 & 7)] = f2h(p0);
          pb[(((2 + (l15 >> 3)) ^ xw) * 8) + (l15 & 7)] = f2h(p1);
        }
      __asm__ volatile("s_waitcnt lgkmcnt(0)" ::: "memory");
      f16x8 ap[4], bv[4];
#pragma unroll
      for (int mt = 0; mt < 4; ++mt)
        ap[mt] = *(const f16x8a*)((const char*)Pw + (mt * 16 + l15) * 64 + (quad ^ xr) * 16);
#pragma unroll
      for (int nt = 0; nt < 4; ++nt)
        bv[nt] = *(const f16x8a*)((const char*)Vt + (nt * 16 + l15) * 448 + cig * 64 + quad * 16);
#pragma unroll
      for (int mt = 0; mt < 4; ++mt)
#pragma unroll
        for (int nt = 0; nt < 4; ++nt)
          o[mt][nt] = __builtin_amdgcn_mfma_f32_16x16x32_f16(ap[mt], bv[nt], o[mt][nt], 0, 0, 0);
    }
    __syncthreads();
  }

#pragma unroll
  for (int mt = 0; mt < 4; ++mt)
#pragma unroll
    for (int rg = 0; rg < 4; ++rg) {
      float l = lsum[mt][rg];
      l += __shfl_xor(l, 1);
      l += __shfl_xor(l, 2);
      l += __shfl_xor(l, 4);
      l += __shfl_xor(l, 8);
      int s = w * 64 + mt * 16 + quad * 4 + rg;
      if (s < 220) {
        float inv = 1.0f / l;
        unsigned short* dst = aout + (tb + s) * 1024 + h * 64;
#pragma unroll
        for (int nt = 0; nt < 4; ++nt) dst[nt * 16 + l15] = f2h(o[mt][nt][rg] * inv);
      }
    }
}

// ---------------------------------------------------------------- temporal attention (prep'd inputs)
// 4 heads per wave (loop), grid 880 = 4 batches x 220 patches. Per-wave LDS
// buffers (Vtw, Pw) are reused sequentially across head iterations — same-wave
// LDS ops complete in order, so no cross-iteration hazard.
__global__ __launch_bounds__(256) void attn_temporal(
    const unsigned short* __restrict__ qkv, unsigned short* __restrict__ aout) {
  __shared__ __align__(16) unsigned short sh[14336];
  const int tid = threadIdx.x;
  const int w = tid >> 6, lane = tid & 63;
  const int l15 = lane & 15, quad = lane >> 4;
  const int b = blockIdx.x / 220;
  const int p = blockIdx.x % 220;
  unsigned short* Vtw = sh + w * 2560;
  unsigned short* Pw = sh + 10240 + w * 1024;
  const size_t fs = (size_t)220 * 3072;
  const int xr = (l15 & 3) ^ ((l15 >> 2) & 3);
  const int okk = l15 < 8;

#pragma unroll 1
  for (int hh = 0; hh < 4; ++hh) {
    const int h = hh * 4 + w;
    const unsigned short* base = qkv + ((size_t)(b * 24) * 220 + p) * 3072 + h * 64;

    {
      int r = lane >> 1, hf = lane & 1;
      if (r < 24) {
        const uint4* src = (const uint4*)(base + r * fs + 2048 + hf * 32);
        uint4 vv[4];
#pragma unroll
        for (int c = 0; c < 4; ++c) vv[c] = src[c];
        const unsigned short* us = (const unsigned short*)vv;
#pragma unroll
        for (int j = 0; j < 32; ++j) Vtw[(hf * 32 + j) * 40 + r] = us[j];
      } else {
#pragma unroll
        for (int j = 0; j < 32; ++j) Vtw[(hf * 32 + j) * 40 + r] = 0;
      }
    }
    f16x8 aq[2][2], bk[2][2];
#pragma unroll
    for (int mt = 0; mt < 2; ++mt) {
      int row = mt * 16 + l15;
      if (row > 23) row = 23;
#pragma unroll
      for (int c = 0; c < 2; ++c)
        aq[mt][c] = *(const f16x8a*)(base + row * fs + c * 32 + quad * 8);
    }
#pragma unroll
    for (int ct = 0; ct < 2; ++ct) {
      int row = ct * 16 + l15;
      if (row > 23) row = 23;
#pragma unroll
      for (int c = 0; c < 2; ++c)
        bk[ct][c] = *(const f16x8a*)(base + row * fs + 1024 + c * 32 + quad * 8);
    }
    f32x4 sc[2][2];
#pragma unroll
    for (int mt = 0; mt < 2; ++mt)
#pragma unroll
      for (int ct = 0; ct < 2; ++ct) {
        f32x4 z = (f32x4){0.f, 0.f, 0.f, 0.f};
        z = __builtin_amdgcn_mfma_f32_16x16x32_f16(aq[mt][0], bk[ct][0], z, 0, 0, 0);
        sc[mt][ct] = __builtin_amdgcn_mfma_f32_16x16x32_f16(aq[mt][1], bk[ct][1], z, 0, 0, 0);
      }
    float lr[2][4];
#pragma unroll
    for (int mt = 0; mt < 2; ++mt)
#pragma unroll
      for (int rg = 0; rg < 4; ++rg) {
        float p0 = exp2f(sc[mt][0][rg]);
        float p1 = okk ? exp2f(sc[mt][1][rg]) : 0.0f;
        float rs = p0 + p1;
        rs += __shfl_xor(rs, 1);
        rs += __shfl_xor(rs, 2);
        rs += __shfl_xor(rs, 4);
        rs += __shfl_xor(rs, 8);
        lr[mt][rg] = rs;
        int xw = quad ^ rg;
        unsigned short* pb = Pw + (mt * 16 + quad * 4 + rg) * 32;
        pb[(((l15 >> 3) ^ xw) * 8) + (l15 & 7)] = f2h(p0);
        pb[(((2 + (l15 >> 3)) ^ xw) * 8) + (l15 & 7)] = f2h(p1);
      }
    __asm__ volatile("s_waitcnt lgkmcnt(0)" ::: "memory");
    f16x8 ap[2], bv[4];
#pragma unroll
    for (int mt = 0; mt < 2; ++mt)
      ap[mt] = *(const f16x8a*)((const char*)Pw + (mt * 16 + l15) * 64 + (quad ^ xr) * 16);
#pragma unroll
    for (int nt = 0; nt < 4; ++nt)
      bv[nt] = *(const f16x8a*)((const char*)Vtw + (nt * 16 + l15) * 80 + quad * 16);
    f32x4 o[2][4];
#pragma unroll
    for (int mt = 0; mt < 2; ++mt)
#pragma unroll
      for (int nt = 0; nt < 4; ++nt) {
        f32x4 z = (f32x4){0.f, 0.f, 0.f, 0.f};
        o[mt][nt] = __builtin_amdgcn_mfma_f32_16x16x32_f16(ap[mt], bv[nt], z, 0, 0, 0);
      }
#pragma unroll
    for (int mt = 0; mt < 2; ++mt)
#pragma unroll
      for (int rg = 0; rg < 4; ++rg) {
        int s = mt * 16 + quad * 4 + rg;
        if (s < 24) {
          float inv = 1.0f / lr[mt][rg];
          unsigned short* dst = aout + ((size_t)(b * 24 + s) * 220 + p) * 1024 + h * 64;
#pragma unroll
          for (int nt = 0; nt < 4; ++nt) dst[nt * 16 + l15] = f2h(o[mt][nt][rg] * inv);
        }
      }
  }
}

// ---------------------------------------------------------------- launch
extern "C" void kernel_launch(void* const* d_in, const int* in_sizes, int n_in,
                              void* d_out, int out_size, void* d_ws, size_t ws_size,
                              hipStream_t stream) {
  (void)in_sizes; (void)n_in; (void)out_size; (void)ws_size;
  const float* x = (const float*)d_in[0];
  const float* wsqkv = (const float*)d_in[1];
  const float* wsproj = (const float*)d_in[2];
  const float* bsproj = (const float*)d_in[3];
  const float* wtqkv = (const float*)d_in[4];
  const float* wtproj = (const float*)d_in[5];
  const float* btproj = (const float*)d_in[6];
  const float* sqg = (const float*)d_in[7];
  const float* skg = (const float*)d_in[8];
  const float* tqg = (const float*)d_in[9];
  const float* tkg = (const float*)d_in[10];

  static bool attr_done = false;
  if (!attr_done) {
    hipFuncSetAttribute(reinterpret_cast<const void*>(gemm256),
                        hipFuncAttributeMaxDynamicSharedMemorySize, 163840);
    attr_done = true;
  }

  char* ws = (char*)d_ws;
  size_t off = 0;
  auto alloc = [&](size_t bytes) {
    char* ptr = ws + off;
    off += (bytes + 255) & ~(size_t)255;
    return ptr;
  };
  unsigned short* xb = (unsigned short*)alloc((size_t)MPAD * 1024 * 2);
  unsigned short* qkvb = (unsigned short*)alloc((size_t)NTOK * 3072 * 2);
  unsigned short* aoutb = (unsigned short*)alloc((size_t)MPAD * 1024 * 2);
  unsigned short* wsqkvb = (unsigned short*)alloc((size_t)3072 * 1024 * 2);
  unsigned short* wsprojTb = (unsigned short*)alloc((size_t)1024 * 1024 * 2);
  unsigned short* wtqkvb = (unsigned short*)alloc((size_t)3072 * 1024 * 2);
  unsigned short* wtprojb = (unsigned short*)alloc((size_t)1024 * 1024 * 2);
  unsigned short* wcb = (unsigned short*)alloc((size_t)3072 * 1024 * 2);
  float* bcb = (float*)alloc(3072 * 4);
  float2* tabS = (float2*)alloc(220 * 32 * 8);
  float2* tabT = (float2*)alloc(24 * 32 * 8);

  // zero the 128 padded A-rows (read by 256-row tiles, never written by casts/attn)
  hipMemsetAsync(xb + (size_t)NTOK * 1024, 0, (size_t)(MPAD - NTOK) * 1024 * 2, stream);
  hipMemsetAsync(aoutb + (size_t)NTOK * 1024, 0, (size_t)(MPAD - NTOK) * 1024 * 2, stream);

  dim3 blk(256);
  cast_kernel<<<21120, blk, 0, stream>>>(x, xb, 5406720);
  cast_kernel<<<3072, blk, 0, stream>>>(wsqkv, wsqkvb, 786432);
  cast_kernel<<<3072, blk, 0, stream>>>(wtqkv, wtqkvb, 786432);
  cast_kernel<<<1024, blk, 0, stream>>>(wtproj, wtprojb, 262144);
  transpose_cast_kernel<<<1024, blk, 0, stream>>>(wsproj, wsprojTb);
  bias_combine_kernel<<<192, blk, 0, stream>>>(wtqkv, bsproj, bcb);
  rope_table_kernel<<<31, blk, 0, stream>>>(tabS, tabT);

  // Wc = Wtqkv * Wsproj  (so qkv_t = out_s * Wc^T + bc) — small, keep 128² kernel
  gemm_bt<<<dim3(24 * 8), blk, 0, stream>>>(wtqkvb, wsprojTb, nullptr, wcb, 3072, 1024, 1024, 0,
                                            nullptr, nullptr, nullptr, 0);

  dim3 blk512(512);
  // stage S: fused QKV + prep  (83 x 12 tiles of 256x256)
  gemm256<<<dim3(83 * 12), blk512, 163840, stream>>>(xb, wsqkvb, nullptr, qkvb, NTOK, 3072, 1024, 3,
                                                     tabS, sqg, skg, 0);
  attn_spatial<<<dim3(1536), blk, 0, stream>>>(qkvb, aoutb);
  // stage T: (proj_S ∘ QKV_T) folded into one GEMM with combined weight + bias, fused prep
  gemm256<<<dim3(83 * 12), blk512, 163840, stream>>>(aoutb, wcb, bcb, qkvb, NTOK, 3072, 1024, 3,
                                                     tabT, tqg, tkg, 1);
  attn_temporal<<<dim3(880), blk, 0, stream>>>(qkvb, aoutb);
  // final projection (83 x 4 tiles)
  gemm256<<<dim3(83 * 4), blk512, 163840, stream>>>(aoutb, wtprojb, btproj, (float*)d_out,
                                                    NTOK, 1024, 1024, 2,
                                                    nullptr, nullptr, nullptr, 0);
}